// Round 1
// baseline (985.112 us; speedup 1.0000x reference)
//
#include <hip/hip_runtime.h>

typedef short short8 __attribute__((ext_vector_type(8)));
typedef float f32x4 __attribute__((ext_vector_type(4)));

#define DEVINL __device__ __forceinline__

// ---------------- host: sedenion sign/index table (Cayley-Dickson) ----------
struct SedTab { signed char s[256]; unsigned char j[256]; };

static void cd_mult_host(const float* a, const float* b, float* r, int n) {
    if (n == 1) { r[0] = a[0] * b[0]; return; }
    int h = n / 2;
    float cb1[8], cb2[8], t1[8], t2[8], t3[8], t4[8];
    cb1[0] = b[0]; for (int i = 1; i < h; ++i) cb1[i] = -b[i];        // conj(b1)
    cb2[0] = b[h]; for (int i = 1; i < h; ++i) cb2[i] = -b[h + i];    // conj(b2)
    cd_mult_host(a,     b,   t1, h);   // a1*b1
    cd_mult_host(cb2,   a+h, t2, h);   // conj(b2)*a2
    cd_mult_host(b+h,   a,   t3, h);   // b2*a1
    cd_mult_host(a+h,   cb1, t4, h);   // a2*conj(b1)
    for (int i = 0; i < h; ++i) { r[i] = t1[i] - t2[i]; r[h + i] = t3[i] + t4[i]; }
}

static SedTab build_sed() {
    SedTab t{};
    for (int i = 0; i < 16; ++i)
        for (int jj = 0; jj < 16; ++jj) {
            float a[16] = {0}, b[16] = {0}, r[16] = {0};
            a[i] = 1.0f; b[jj] = 1.0f;
            cd_mult_host(a, b, r, 16);
            for (int k = 0; k < 16; ++k)
                if (r[k] != 0.0f) {
                    t.s[i * 16 + k] = (r[k] > 0.f) ? 1 : -1;
                    t.j[i * 16 + k] = (unsigned char)jj;
                }
        }
    return t;
}
static const SedTab g_sed = build_sed();

// ---------------- device helpers -------------------------------------------
DEVINL unsigned short f2bf(float v) {
    union { float f; unsigned int u; } c; c.f = v;
    unsigned int r = (c.u + 0x7FFFu + ((c.u >> 16) & 1u)) >> 16;
    return (unsigned short)r;
}

DEVINL float gelu_f(float v) {   // tanh-approx == v*sigmoid(1.5958(v+0.044715v^3)), |err|<1.1e-3
    float u = 1.5957691216f * (v + 0.044715f * v * v * v);
    return v / (1.0f + __expf(-u));
}

DEVINL void gl2lds16(const void* g, void* l) {
    __builtin_amdgcn_global_load_lds((__attribute__((address_space(1))) const unsigned int*)g,
                                     (__attribute__((address_space(3))) unsigned int*)l, 16, 0, 0);
}

// ---------------- wfT builder: wfT[n=(k,e)][kk=(i,dd)] = s(i,k)*w_sed[j,dd,e]
__global__ __launch_bounds__(256) void build_wft(const float* __restrict__ w_sed,
                                                 unsigned short* __restrict__ wfT,
                                                 SedTab tab) {
    __shared__ float t[32][33];
    int n0 = blockIdx.y * 32, kk0 = blockIdx.x * 32;
    int k = n0 / 192, i = kk0 / 192;            // tiles never straddle (192 = 6*32)
    int j = tab.j[i * 16 + k];
    float s = (float)tab.s[i * 16 + k];
    int e0 = n0 - k * 192, dd0 = kk0 - i * 192;
    int tx = threadIdx.x & 31, ty = threadIdx.x >> 5;
    const float* base = w_sed + ((size_t)j * 192 + dd0) * 192 + e0;
    for (int it = 0; it < 4; ++it) {
        int row = ty + it * 8;                  // row = dd index, tx = e index
        t[row][tx] = base[(size_t)row * 192 + tx];
    }
    __syncthreads();
    unsigned short* ob = wfT + (size_t)n0 * 3072 + kk0;
    for (int it = 0; it < 4; ++it) {
        int row = ty + it * 8;                  // out row = e index, tx = dd index
        ob[(size_t)row * 3072 + tx] = f2bf(s * t[tx][row]);
    }
}

// ---------------- small weights → [N][K] bf16 -------------------------------
__global__ __launch_bounds__(256) void prep_w(const float* __restrict__ proj,
                                              const float* __restrict__ fc1,
                                              const float* __restrict__ fc2,
                                              unsigned short* __restrict__ projT,
                                              unsigned short* __restrict__ fc1T,
                                              unsigned short* __restrict__ fc2T) {
    int t = blockIdx.x * 256 + threadIdx.x;     // grid covers 147456
    if (t < 192 * 192) projT[t] = f2bf(proj[(t % 192) * 192 + t / 192]);
    if (t < 768 * 192) fc1T[t]  = f2bf(fc1 [(t % 192) * 768 + t / 192]);
    if (t < 192 * 768) fc2T[t]  = f2bf(fc2 [(t % 768) * 192 + t / 768]);
}

// ---------------- LN1 over channels + windowize; also emit raw x in windowed order
__global__ __launch_bounds__(256) void ln1_win(const float* __restrict__ x,
                                               const float* __restrict__ g,
                                               const float* __restrict__ bta,
                                               unsigned short* __restrict__ xw,
                                               float* __restrict__ xwin) {
    __shared__ float vals[192 * 65];
    __shared__ float ps[8][64];
    __shared__ float mrs[2][64];
    int t = threadIdx.x;
    int bid = blockIdx.x;
    int x0 = (bid & 3) << 6;
    int y  = (bid >> 2) & 255;
    int b  = bid >> 10;
    int px = t & 63, cg = t >> 6;
    const float* xp = x + ((size_t)b * 192 * 65536) + (size_t)y * 256 + x0 + px;
    float s = 0.f, s2 = 0.f;
    for (int c = cg; c < 192; c += 4) {
        float v = xp[(size_t)c * 65536];
        vals[c * 65 + px] = v;
        s += v; s2 += v * v;
    }
    ps[cg][px] = s; ps[cg + 4][px] = s2;
    __syncthreads();
    if (t < 64) {
        float S  = ps[0][t] + ps[1][t] + ps[2][t] + ps[3][t];
        float S2 = ps[4][t] + ps[5][t] + ps[6][t] + ps[7][t];
        float mean = S * (1.0f / 192.0f);
        float var  = S2 * (1.0f / 192.0f) - mean * mean;
        mrs[0][t] = mean;
        mrs[1][t] = rsqrtf(var + 1e-5f);
    }
    __syncthreads();
    int wh = y >> 2, wr = y & 3;
    for (int i = t; i < 192 * 64; i += 256) {
        int p = i / 192;
        int c = i - p * 192;
        float v = vals[c * 65 + p];
        int xx = x0 + p;
        int ww = xx >> 2, wc = xx & 3;
        int gp = ((b * 64 + wh) * 64 + ww) * 16 + wr * 4 + wc;
        size_t o = (size_t)gp * 192 + c;
        xwin[o] = v;
        xw[o] = f2bf((v - mrs[0][p]) * mrs[1][p] * g[c] + bta[c]);
    }
}

// ---------------- LN over contiguous rows [M,192] → bf16 --------------------
__global__ __launch_bounds__(192) void ln_rows(const float* __restrict__ in,
                                               const float* __restrict__ g,
                                               const float* __restrict__ bta,
                                               unsigned short* __restrict__ outb) {
    int t = threadIdx.x, lane = t & 63, wid = t >> 6;
    __shared__ float rs[3], rs2[3];
    float gg = g[t], bb = bta[t];
    size_t row0 = (size_t)blockIdx.x * 16;
    for (int rr = 0; rr < 16; ++rr) {
        size_t row = row0 + rr;
        float v = in[row * 192 + t];
        float s = v, s2 = v * v;
        #pragma unroll
        for (int o = 32; o; o >>= 1) { s += __shfl_xor(s, o, 64); s2 += __shfl_xor(s2, o, 64); }
        if (lane == 0) { rs[wid] = s; rs2[wid] = s2; }
        __syncthreads();
        float S = rs[0] + rs[1] + rs[2], S2 = rs2[0] + rs2[1] + rs2[2];
        float mean = S * (1.0f / 192.0f);
        float var  = S2 * (1.0f / 192.0f) - mean * mean;
        outb[row * 192 + t] = f2bf((v - mean) * rsqrtf(var + 1e-5f) * gg + bb);
        __syncthreads();
    }
}

// ---------------- bf16 MFMA GEMM, TM=128 x TN, BK=64, XOR-swizzled LDS ------
// A:[M,K] row-major bf16, BT:[N,K] row-major bf16 (pre-transposed B).
// EPI 0: out bf16 = gelu(acc [+bias])         (gemm1 sedenion, gemm3 fc1)
// EPI 1: xres[r,c] += acc + bias[c]           (gemm2 proj, residual in-place)
// EPI 2: d_out[BCHW] = xres[r,c] + acc + bias (gemm4 fc2, final scatter)
template<int TN, int EPI>
__global__ __launch_bounds__(256, 2) void gemm_bf16(
        const unsigned short* __restrict__ A, const unsigned short* __restrict__ BT,
        const float* __restrict__ bias, unsigned short* __restrict__ outB,
        float* __restrict__ xres, float* __restrict__ outF,
        int K, int N, int rowOff) {
    constexpr int TM = 128;
    constexpr int WN = TN / 2;
    constexpr int NT = WN / 16;
    __shared__ short lsA[TM * 64];
    __shared__ short lsB[TN * 64];
    int tid = threadIdx.x, lane = tid & 63, wid = tid >> 6;
    int wrow = wid >> 1, wcol = wid & 1;
    int lm = lane & 15, lq = lane >> 4;
    int bm = blockIdx.x * TM, bn = blockIdx.y * TN;
    const unsigned short* Ag = A + (size_t)bm * K;
    const unsigned short* Bg = BT + (size_t)bn * K;
    f32x4 acc[4][NT] = {};
    for (int k0 = 0; k0 < K; k0 += 64) {
        #pragma unroll
        for (int it = 0; it < TM / 32; ++it) {      // stage A tile
            int p = (it * 4 + wid) * 64 + lane;
            int r = p >> 3;
            int q = (p & 7) ^ (r & 7);
            gl2lds16(Ag + (size_t)r * K + k0 + q * 8, lsA + (it * 4 + wid) * 512);
        }
        #pragma unroll
        for (int it = 0; it < TN / 32; ++it) {      // stage BT tile
            int p = (it * 4 + wid) * 64 + lane;
            int r = p >> 3;
            int q = (p & 7) ^ (r & 7);
            gl2lds16(Bg + (size_t)r * K + k0 + q * 8, lsB + (it * 4 + wid) * 512);
        }
        __syncthreads();
        #pragma unroll
        for (int s = 0; s < 2; ++s) {
            short8 af[4], bfr[NT];
            #pragma unroll
            for (int mt = 0; mt < 4; ++mt) {
                int r = wrow * 64 + mt * 16 + lm;
                int q = s * 4 + lq;
                int pos = r * 8 + (q ^ (r & 7));
                af[mt] = *(const short8*)&lsA[pos * 8];
            }
            #pragma unroll
            for (int nt = 0; nt < NT; ++nt) {
                int r = wcol * WN + nt * 16 + lm;
                int q = s * 4 + lq;
                int pos = r * 8 + (q ^ (r & 7));
                bfr[nt] = *(const short8*)&lsB[pos * 8];
            }
            #pragma unroll
            for (int mt = 0; mt < 4; ++mt)
                #pragma unroll
                for (int nt = 0; nt < NT; ++nt)
                    acc[mt][nt] = __builtin_amdgcn_mfma_f32_16x16x32_bf16(af[mt], bfr[nt], acc[mt][nt], 0, 0, 0);
        }
        __syncthreads();
    }
    // epilogue: C/D layout col=lane&15, row=lq*4+reg
    int rowB = bm + wrow * 64 + lq * 4;
    int colB = bn + wcol * WN + lm;
    #pragma unroll
    for (int mt = 0; mt < 4; ++mt)
        #pragma unroll
        for (int nt = 0; nt < NT; ++nt)
            #pragma unroll
            for (int r = 0; r < 4; ++r) {
                int gr = rowB + mt * 16 + r;
                int gc = colB + nt * 16;
                float v = acc[mt][nt][r];
                if constexpr (EPI == 0) {
                    if (bias) v += bias[gc];
                    outB[(size_t)gr * N + gc] = f2bf(gelu_f(v));
                } else if constexpr (EPI == 1) {
                    size_t o = (size_t)gr * 192 + gc;
                    xres[o] = xres[o] + v + bias[gc];
                } else {
                    int grow = rowOff + gr;
                    float tv = xres[(size_t)grow * 192 + gc] + v + bias[gc];
                    int b  = grow >> 16;
                    int wh = (grow >> 10) & 63;
                    int ww = (grow >> 4) & 63;
                    int q2 = grow & 15;
                    int y  = wh * 4 + (q2 >> 2);
                    int xx = ww * 4 + (q2 & 3);
                    outF[(((size_t)b * 192 + gc) * 256 + y) * 256 + xx] = tv;
                }
            }
}

// ---------------- launch ----------------------------------------------------
extern "C" void kernel_launch(void* const* d_in, const int* in_sizes, int n_in,
                              void* d_out, int out_size, void* d_ws, size_t ws_size,
                              hipStream_t stream) {
    const float* x      = (const float*)d_in[0];
    const float* n1g    = (const float*)d_in[1];
    const float* n1b    = (const float*)d_in[2];
    const float* w_sed  = (const float*)d_in[3];
    const float* proj_w = (const float*)d_in[4];
    const float* proj_b = (const float*)d_in[5];
    const float* n2g    = (const float*)d_in[6];
    const float* n2b    = (const float*)d_in[7];
    const float* fc1_w  = (const float*)d_in[8];
    const float* fc1_b  = (const float*)d_in[9];
    const float* fc2_w  = (const float*)d_in[10];
    const float* fc2_b  = (const float*)d_in[11];
    float* out = (float*)d_out;

    char* ws = (char*)d_ws;
    unsigned short* wfT   = (unsigned short*)(ws);                 // 18,874,368 B
    unsigned short* xw    = (unsigned short*)(ws + 18874368);      // 50,331,648 B (later H1 chunk)
    unsigned short* A2    = (unsigned short*)(ws + 69206016);      // 50,331,648 B (later A3)
    float*          xres  = (float*)        (ws + 119537664);     // 100,663,296 B
    unsigned short* projT = (unsigned short*)(ws + 220200960);     // 73,728 B
    unsigned short* fc1T  = (unsigned short*)(ws + 220274688);     // 294,912 B
    unsigned short* fc2T  = (unsigned short*)(ws + 220569600);     // 294,912 B  (end 220,864,512)
    unsigned short* H1c   = xw;
    unsigned short* A3    = A2;

    build_wft<<<dim3(96, 96), 256, 0, stream>>>(w_sed, wfT, g_sed);
    prep_w<<<576, 256, 0, stream>>>(proj_w, fc1_w, fc2_w, projT, fc1T, fc2T);
    ln1_win<<<2048, 256, 0, stream>>>(x, n1g, n1b, xw, xres);

    // sedenion GEMM: [8192,3072]@[3072,3072] → gelu → A2 (≡ [131072,192])
    gemm_bf16<128, 0><<<dim3(64, 24), 256, 0, stream>>>(xw, wfT, nullptr, A2,
                                                        nullptr, nullptr, 3072, 3072, 0);
    // proj GEMM + residual: xres += A2@projT + proj_b
    gemm_bf16<192, 1><<<dim3(1024, 1), 256, 0, stream>>>(A2, projT, proj_b, nullptr,
                                                         xres, nullptr, 192, 192, 0);
    // LN2: xres → A3 bf16
    ln_rows<<<8192, 192, 0, stream>>>(xres, n2g, n2b, A3);
    // FFN, 4 row-chunks of 32768 (H1 chunk reuses xw buffer)
    for (int c = 0; c < 4; ++c) {
        const unsigned short* A3c = A3 + (size_t)c * 32768 * 192;
        gemm_bf16<128, 0><<<dim3(256, 6), 256, 0, stream>>>(A3c, fc1T, fc1_b, H1c,
                                                            nullptr, nullptr, 192, 768, 0);
        gemm_bf16<192, 2><<<dim3(256, 1), 256, 0, stream>>>(H1c, fc2T, fc2_b, nullptr,
                                                            xres, out, 768, 192, c * 32768);
    }
}

// Round 2
// 775.565 us; speedup vs baseline: 1.2702x; 1.2702x over previous
//
#include <hip/hip_runtime.h>

typedef short short8 __attribute__((ext_vector_type(8)));
typedef float f32x4 __attribute__((ext_vector_type(4)));

#define DEVINL __device__ __forceinline__

// ---------------- host: sedenion sign/index table (Cayley-Dickson) ----------
struct SedTab { signed char s[256]; unsigned char j[256]; };

static void cd_mult_host(const float* a, const float* b, float* r, int n) {
    if (n == 1) { r[0] = a[0] * b[0]; return; }
    int h = n / 2;
    float cb1[8], cb2[8], t1[8], t2[8], t3[8], t4[8];
    cb1[0] = b[0]; for (int i = 1; i < h; ++i) cb1[i] = -b[i];        // conj(b1)
    cb2[0] = b[h]; for (int i = 1; i < h; ++i) cb2[i] = -b[h + i];    // conj(b2)
    cd_mult_host(a,     b,   t1, h);   // a1*b1
    cd_mult_host(cb2,   a+h, t2, h);   // conj(b2)*a2
    cd_mult_host(b+h,   a,   t3, h);   // b2*a1
    cd_mult_host(a+h,   cb1, t4, h);   // a2*conj(b1)
    for (int i = 0; i < h; ++i) { r[i] = t1[i] - t2[i]; r[h + i] = t3[i] + t4[i]; }
}

static SedTab build_sed() {
    SedTab t{};
    for (int i = 0; i < 16; ++i)
        for (int jj = 0; jj < 16; ++jj) {
            float a[16] = {0}, b[16] = {0}, r[16] = {0};
            a[i] = 1.0f; b[jj] = 1.0f;
            cd_mult_host(a, b, r, 16);
            for (int k = 0; k < 16; ++k)
                if (r[k] != 0.0f) {
                    t.s[i * 16 + k] = (r[k] > 0.f) ? 1 : -1;
                    t.j[i * 16 + k] = (unsigned char)jj;
                }
        }
    return t;
}
static const SedTab g_sed = build_sed();

// ---------------- device helpers -------------------------------------------
DEVINL unsigned short f2bf(float v) {
    union { float f; unsigned int u; } c; c.f = v;
    unsigned int r = (c.u + 0x7FFFu + ((c.u >> 16) & 1u)) >> 16;
    return (unsigned short)r;
}

DEVINL float gelu_f(float v) {   // tanh-approx == v*sigmoid(1.5958(v+0.044715v^3)), |err|<1.1e-3
    float u = 1.5957691216f * (v + 0.044715f * v * v * v);
    return v / (1.0f + __expf(-u));
}

DEVINL void gl2lds16(const void* g, void* l) {
    __builtin_amdgcn_global_load_lds((__attribute__((address_space(1))) const unsigned int*)g,
                                     (__attribute__((address_space(3))) unsigned int*)l, 16, 0, 0);
}

// ---------------- wfT builder: wfT[n=(k,e)][kk=(i,dd)] = s(i,k)*w_sed[j,dd,e]
__global__ __launch_bounds__(256) void build_wft(const float* __restrict__ w_sed,
                                                 unsigned short* __restrict__ wfT,
                                                 SedTab tab) {
    __shared__ float t[32][33];
    int n0 = blockIdx.y * 32, kk0 = blockIdx.x * 32;
    int k = n0 / 192, i = kk0 / 192;            // tiles never straddle (192 = 6*32)
    int j = tab.j[i * 16 + k];
    float s = (float)tab.s[i * 16 + k];
    int e0 = n0 - k * 192, dd0 = kk0 - i * 192;
    int tx = threadIdx.x & 31, ty = threadIdx.x >> 5;
    const float* base = w_sed + ((size_t)j * 192 + dd0) * 192 + e0;
    for (int it = 0; it < 4; ++it) {
        int row = ty + it * 8;                  // row = dd index, tx = e index
        t[row][tx] = base[(size_t)row * 192 + tx];
    }
    __syncthreads();
    unsigned short* ob = wfT + (size_t)n0 * 3072 + kk0;
    for (int it = 0; it < 4; ++it) {
        int row = ty + it * 8;                  // out row = e index, tx = dd index
        ob[(size_t)row * 3072 + tx] = f2bf(s * t[tx][row]);
    }
}

// ---------------- small weights → [N][K] bf16 -------------------------------
__global__ __launch_bounds__(256) void prep_w(const float* __restrict__ proj,
                                              const float* __restrict__ fc1,
                                              const float* __restrict__ fc2,
                                              unsigned short* __restrict__ projT,
                                              unsigned short* __restrict__ fc1T,
                                              unsigned short* __restrict__ fc2T) {
    int t = blockIdx.x * 256 + threadIdx.x;     // grid covers 147456
    if (t < 192 * 192) projT[t] = f2bf(proj[(t % 192) * 192 + t / 192]);
    if (t < 768 * 192) fc1T[t]  = f2bf(fc1 [(t % 192) * 768 + t / 192]);
    if (t < 192 * 768) fc2T[t]  = f2bf(fc2 [(t % 768) * 192 + t / 768]);
}

// ---------------- LN1 over channels + windowize; also emit raw x in windowed order
__global__ __launch_bounds__(256) void ln1_win(const float* __restrict__ x,
                                               const float* __restrict__ g,
                                               const float* __restrict__ bta,
                                               unsigned short* __restrict__ xw,
                                               float* __restrict__ xwin) {
    __shared__ float vals[192 * 65];
    __shared__ float ps[8][64];
    __shared__ float mrs[2][64];
    int t = threadIdx.x;
    int bid = blockIdx.x;
    int x0 = (bid & 3) << 6;
    int y  = (bid >> 2) & 255;
    int b  = bid >> 10;
    int px = t & 63, cg = t >> 6;
    const float* xp = x + ((size_t)b * 192 * 65536) + (size_t)y * 256 + x0 + px;
    float s = 0.f, s2 = 0.f;
    for (int c = cg; c < 192; c += 4) {
        float v = xp[(size_t)c * 65536];
        vals[c * 65 + px] = v;
        s += v; s2 += v * v;
    }
    ps[cg][px] = s; ps[cg + 4][px] = s2;
    __syncthreads();
    if (t < 64) {
        float S  = ps[0][t] + ps[1][t] + ps[2][t] + ps[3][t];
        float S2 = ps[4][t] + ps[5][t] + ps[6][t] + ps[7][t];
        float mean = S * (1.0f / 192.0f);
        float var  = S2 * (1.0f / 192.0f) - mean * mean;
        mrs[0][t] = mean;
        mrs[1][t] = rsqrtf(var + 1e-5f);
    }
    __syncthreads();
    int wh = y >> 2, wr = y & 3;
    for (int i = t; i < 192 * 64; i += 256) {
        int p = i / 192;
        int c = i - p * 192;
        float v = vals[c * 65 + p];
        int xx = x0 + p;
        int ww = xx >> 2, wc = xx & 3;
        int gp = ((b * 64 + wh) * 64 + ww) * 16 + wr * 4 + wc;
        size_t o = (size_t)gp * 192 + c;
        xwin[o] = v;
        xw[o] = f2bf((v - mrs[0][p]) * mrs[1][p] * g[c] + bta[c]);
    }
}

// ---------------- bf16 MFMA GEMM, TM x TN, BK=64, XOR-swizzled LDS ----------
// A:[M,K] row-major bf16, BT:[N,K] row-major bf16 (pre-transposed B).
// EPI 0: outB bf16 = gelu(acc [+bias])                (gemm1 sedenion, gemm3 fc1)
// EPI 2: out BCHW float4 = xres + acc + bias          (gemm4 fc2, LDS-transposed)
// EPI 3: xres += acc+bias; outB = LN2(xres) bf16      (gemm2 proj + fused LN2)
template<int TM, int TN, int EPI>
__global__ __launch_bounds__(256, 2) void gemm_bf16(
        const unsigned short* __restrict__ A, const unsigned short* __restrict__ BT,
        const float* __restrict__ bias, unsigned short* __restrict__ outB,
        float* __restrict__ xres, float* __restrict__ outF,
        const float* __restrict__ g2, const float* __restrict__ b2,
        int K, int N, int rowOff) {
    constexpr int WN = TN / 2;
    constexpr int NT = WN / 16;
    constexpr int MT = TM / 32;
    constexpr int HR = TM / 2;
    constexpr int STAG = (TM * 64 + TN * 64) * 2;          // staging bytes
    constexpr int TBY  = (EPI == 2) ? 64 * 201 * 4 : 0;    // transpose buffer
    constexpr int SBY  = STAG > TBY ? STAG : TBY;
    __shared__ __align__(16) char smem[SBY];
    short* lsA = (short*)smem;
    short* lsB = (short*)(smem + TM * 64 * 2);
    int tid = threadIdx.x, lane = tid & 63, wid = tid >> 6;
    int wrow = wid >> 1, wcol = wid & 1;
    int lm = lane & 15, lq = lane >> 4;
    int bm = blockIdx.x * TM, bn = blockIdx.y * TN;
    const unsigned short* Ag = A + (size_t)bm * K;
    const unsigned short* Bg = BT + (size_t)bn * K;
    f32x4 acc[MT][NT] = {};
    for (int k0 = 0; k0 < K; k0 += 64) {
        #pragma unroll
        for (int it = 0; it < TM / 32; ++it) {      // stage A tile
            int p = (it * 4 + wid) * 64 + lane;
            int r = p >> 3;
            int q = (p & 7) ^ (r & 7);
            gl2lds16(Ag + (size_t)r * K + k0 + q * 8, lsA + (it * 4 + wid) * 512);
        }
        #pragma unroll
        for (int it = 0; it < TN / 32; ++it) {      // stage BT tile
            int p = (it * 4 + wid) * 64 + lane;
            int r = p >> 3;
            int q = (p & 7) ^ (r & 7);
            gl2lds16(Bg + (size_t)r * K + k0 + q * 8, lsB + (it * 4 + wid) * 512);
        }
        __syncthreads();
        #pragma unroll
        for (int s = 0; s < 2; ++s) {
            short8 af[MT], bfr[NT];
            #pragma unroll
            for (int mt = 0; mt < MT; ++mt) {
                int r = wrow * HR + mt * 16 + lm;
                int q = s * 4 + lq;
                int pos = r * 8 + (q ^ (r & 7));
                af[mt] = *(const short8*)&lsA[pos * 8];
            }
            #pragma unroll
            for (int nt = 0; nt < NT; ++nt) {
                int r = wcol * WN + nt * 16 + lm;
                int q = s * 4 + lq;
                int pos = r * 8 + (q ^ (r & 7));
                bfr[nt] = *(const short8*)&lsB[pos * 8];
            }
            #pragma unroll
            for (int mt = 0; mt < MT; ++mt)
                #pragma unroll
                for (int nt = 0; nt < NT; ++nt)
                    acc[mt][nt] = __builtin_amdgcn_mfma_f32_16x16x32_bf16(af[mt], bfr[nt], acc[mt][nt], 0, 0, 0);
        }
        __syncthreads();
    }
    // epilogue: C/D layout col=lane&15, row=lq*4+reg
    int rowB = bm + wrow * HR + lq * 4;
    int colB = bn + wcol * WN + lm;

    if constexpr (EPI == 0) {
        #pragma unroll
        for (int mt = 0; mt < MT; ++mt)
            #pragma unroll
            for (int nt = 0; nt < NT; ++nt)
                #pragma unroll
                for (int r = 0; r < 4; ++r) {
                    int gr = rowB + mt * 16 + r;
                    int gc = colB + nt * 16;
                    float v = acc[mt][nt][r];
                    if (bias) v += bias[gc];
                    outB[(size_t)gr * N + gc] = f2bf(gelu_f(v));
                }
    } else if constexpr (EPI == 2) {
        // fc2 + residual + scatter-to-BCHW via LDS transpose. TM=64, TN=192, bn=0.
        float* T = (float*)smem;                 // [64][201]
        #pragma unroll
        for (int mt = 0; mt < MT; ++mt)
            #pragma unroll
            for (int nt = 0; nt < NT; ++nt)
                #pragma unroll
                for (int r = 0; r < 4; ++r) {
                    int grl = wrow * HR + mt * 16 + lq * 4 + r;
                    int gc = colB + nt * 16;
                    int grow = rowOff + bm + grl;
                    float v = xres[(size_t)grow * 192 + gc] + acc[mt][nt][r] + bias[gc];
                    T[grl * 201 + gc] = v;
                }
        __syncthreads();
        int g0 = rowOff + bm;                    // multiple of 64
        int b  = g0 >> 16;
        int wh = (g0 >> 10) & 63;
        int ww0 = (g0 >> 4) & 63;                // multiple of 4
        int ybase = wh * 4, xbase = ww0 * 4;
        for (int idx = tid; idx < 3072; idx += 256) {
            int xq = idx & 3, run = idx >> 2;
            int c = run >> 2, wr = run & 3;
            int p = xq * 16 + wr * 4;
            f32x4 val;
            val[0] = T[(p + 0) * 201 + c];
            val[1] = T[(p + 1) * 201 + c];
            val[2] = T[(p + 2) * 201 + c];
            val[3] = T[(p + 3) * 201 + c];
            size_t o = (((size_t)b * 192 + c) * 256 + (ybase + wr)) * 256 + xbase + xq * 4;
            *(f32x4*)&outF[o] = val;
        }
    } else {
        // proj + residual into xres, fused LN2 → outB (A3). TM=128, TN=192, bn=0.
        float sA[MT][4], s2A[MT][4];
        #pragma unroll
        for (int mt = 0; mt < MT; ++mt)
            #pragma unroll
            for (int r = 0; r < 4; ++r) { sA[mt][r] = 0.f; s2A[mt][r] = 0.f; }
        #pragma unroll
        for (int mt = 0; mt < MT; ++mt)
            #pragma unroll
            for (int nt = 0; nt < NT; ++nt)
                #pragma unroll
                for (int r = 0; r < 4; ++r) {
                    int gr = rowB + mt * 16 + r;
                    int gc = colB + nt * 16;
                    size_t o = (size_t)gr * 192 + gc;
                    float v = xres[o] + acc[mt][nt][r] + bias[gc];
                    xres[o] = v;
                    acc[mt][nt][r] = v;
                    sA[mt][r] += v; s2A[mt][r] += v * v;
                }
        #pragma unroll
        for (int mt = 0; mt < MT; ++mt)
            #pragma unroll
            for (int r = 0; r < 4; ++r)
                #pragma unroll
                for (int msk = 1; msk < 16; msk <<= 1) {
                    sA[mt][r]  += __shfl_xor(sA[mt][r],  msk, 64);
                    s2A[mt][r] += __shfl_xor(s2A[mt][r], msk, 64);
                }
        float* psS   = (float*)smem;             // [128][2]
        float* psS2  = psS + 256;                // [128][2]
        float* pmean = psS2 + 256;               // [128]
        float* prsig = pmean + 128;              // [128]
        if (lm == 0) {
            #pragma unroll
            for (int mt = 0; mt < MT; ++mt)
                #pragma unroll
                for (int r = 0; r < 4; ++r) {
                    int rl = wrow * HR + mt * 16 + lq * 4 + r;
                    psS [rl * 2 + wcol] = sA[mt][r];
                    psS2[rl * 2 + wcol] = s2A[mt][r];
                }
        }
        __syncthreads();
        if (tid < TM) {
            float S  = psS[tid * 2]  + psS[tid * 2 + 1];
            float S2 = psS2[tid * 2] + psS2[tid * 2 + 1];
            float mean = S * (1.0f / 192.0f);
            float var  = S2 * (1.0f / 192.0f) - mean * mean;
            pmean[tid] = mean;
            prsig[tid] = rsqrtf(var + 1e-5f);
        }
        __syncthreads();
        float gw[NT], bw[NT];
        #pragma unroll
        for (int nt = 0; nt < NT; ++nt) {
            int gc = colB + nt * 16;
            gw[nt] = g2[gc]; bw[nt] = b2[gc];
        }
        #pragma unroll
        for (int mt = 0; mt < MT; ++mt)
            #pragma unroll
            for (int nt = 0; nt < NT; ++nt)
                #pragma unroll
                for (int r = 0; r < 4; ++r) {
                    int gr = rowB + mt * 16 + r;
                    int rl = wrow * HR + mt * 16 + lq * 4 + r;
                    int gc = colB + nt * 16;
                    float v = (acc[mt][nt][r] - pmean[rl]) * prsig[rl] * gw[nt] + bw[nt];
                    outB[(size_t)gr * 192 + gc] = f2bf(v);
                }
    }
}

// ---------------- launch ----------------------------------------------------
extern "C" void kernel_launch(void* const* d_in, const int* in_sizes, int n_in,
                              void* d_out, int out_size, void* d_ws, size_t ws_size,
                              hipStream_t stream) {
    const float* x      = (const float*)d_in[0];
    const float* n1g    = (const float*)d_in[1];
    const float* n1b    = (const float*)d_in[2];
    const float* w_sed  = (const float*)d_in[3];
    const float* proj_w = (const float*)d_in[4];
    const float* proj_b = (const float*)d_in[5];
    const float* n2g    = (const float*)d_in[6];
    const float* n2b    = (const float*)d_in[7];
    const float* fc1_w  = (const float*)d_in[8];
    const float* fc1_b  = (const float*)d_in[9];
    const float* fc2_w  = (const float*)d_in[10];
    const float* fc2_b  = (const float*)d_in[11];
    float* out = (float*)d_out;

    char* ws = (char*)d_ws;
    unsigned short* wfT   = (unsigned short*)(ws);                 // 18,874,368 B
    unsigned short* xw    = (unsigned short*)(ws + 18874368);      // 50,331,648 B (later H1 chunk)
    unsigned short* A2    = (unsigned short*)(ws + 69206016);      // 50,331,648 B (later A3, aliased safely)
    float*          xres  = (float*)        (ws + 119537664);     // 100,663,296 B
    unsigned short* projT = (unsigned short*)(ws + 220200960);     // 73,728 B
    unsigned short* fc1T  = (unsigned short*)(ws + 220274688);     // 294,912 B
    unsigned short* fc2T  = (unsigned short*)(ws + 220569600);     // 294,912 B  (end 220,864,512)
    unsigned short* H1c   = xw;
    unsigned short* A3    = A2;   // EPI3 writes A3 rows only after reading same A2 rows — safe

    build_wft<<<dim3(96, 96), 256, 0, stream>>>(w_sed, wfT, g_sed);
    prep_w<<<576, 256, 0, stream>>>(proj_w, fc1_w, fc2_w, projT, fc1T, fc2T);
    ln1_win<<<2048, 256, 0, stream>>>(x, n1g, n1b, xw, xres);

    // sedenion GEMM: [8192,3072]@[3072,3072] → gelu → A2 (≡ [131072,192])
    gemm_bf16<128, 128, 0><<<dim3(64, 24), 256, 0, stream>>>(
        xw, wfT, nullptr, A2, nullptr, nullptr, nullptr, nullptr, 3072, 3072, 0);
    // proj GEMM + residual + fused LN2: xres += A2@projT + proj_b; A3 = LN2(xres)
    gemm_bf16<128, 192, 3><<<dim3(1024, 1), 256, 0, stream>>>(
        A2, projT, proj_b, A3, xres, nullptr, n2g, n2b, 192, 192, 0);
    // FFN, 4 row-chunks of 32768 (H1 chunk reuses xw buffer)
    for (int c = 0; c < 4; ++c) {
        const unsigned short* A3c = A3 + (size_t)c * 32768 * 192;
        gemm_bf16<128, 128, 0><<<dim3(256, 6), 256, 0, stream>>>(
            A3c, fc1T, fc1_b, H1c, nullptr, nullptr, nullptr, nullptr, 192, 768, 0);
        gemm_bf16<64, 192, 2><<<dim3(512, 1), 256, 0, stream>>>(
            H1c, fc2T, fc2_b, nullptr, xres, out, nullptr, nullptr, 768, 192, c * 32768);
    }
}

// Round 3
// 623.268 us; speedup vs baseline: 1.5806x; 1.2444x over previous
//
#include <hip/hip_runtime.h>

typedef short short8 __attribute__((ext_vector_type(8)));
typedef float f32x4 __attribute__((ext_vector_type(4)));

#define DEVINL __device__ __forceinline__

// ---------------- host: sedenion sign/index table (Cayley-Dickson) ----------
struct SedTab { signed char s[256]; unsigned char j[256]; };

static void cd_mult_host(const float* a, const float* b, float* r, int n) {
    if (n == 1) { r[0] = a[0] * b[0]; return; }
    int h = n / 2;
    float cb1[8], cb2[8], t1[8], t2[8], t3[8], t4[8];
    cb1[0] = b[0]; for (int i = 1; i < h; ++i) cb1[i] = -b[i];        // conj(b1)
    cb2[0] = b[h]; for (int i = 1; i < h; ++i) cb2[i] = -b[h + i];    // conj(b2)
    cd_mult_host(a,     b,   t1, h);   // a1*b1
    cd_mult_host(cb2,   a+h, t2, h);   // conj(b2)*a2
    cd_mult_host(b+h,   a,   t3, h);   // b2*a1
    cd_mult_host(a+h,   cb1, t4, h);   // a2*conj(b1)
    for (int i = 0; i < h; ++i) { r[i] = t1[i] - t2[i]; r[h + i] = t3[i] + t4[i]; }
}

static SedTab build_sed() {
    SedTab t{};
    for (int i = 0; i < 16; ++i)
        for (int jj = 0; jj < 16; ++jj) {
            float a[16] = {0}, b[16] = {0}, r[16] = {0};
            a[i] = 1.0f; b[jj] = 1.0f;
            cd_mult_host(a, b, r, 16);
            for (int k = 0; k < 16; ++k)
                if (r[k] != 0.0f) {
                    t.s[i * 16 + k] = (r[k] > 0.f) ? 1 : -1;
                    t.j[i * 16 + k] = (unsigned char)jj;
                }
        }
    return t;
}
static const SedTab g_sed = build_sed();

// ---------------- device helpers -------------------------------------------
DEVINL unsigned short f2bf(float v) {
    union { float f; unsigned int u; } c; c.f = v;
    unsigned int r = (c.u + 0x7FFFu + ((c.u >> 16) & 1u)) >> 16;
    return (unsigned short)r;
}
DEVINL float bf2f(unsigned short u) {
    union { unsigned int i; float f; } c; c.i = ((unsigned int)u) << 16; return c.f;
}

DEVINL float gelu_f(float v) {   // tanh-approx == v*sigmoid(1.5958(v+0.044715v^3)), |err|<1.1e-3
    float u = 1.5957691216f * (v + 0.044715f * v * v * v);
    return v / (1.0f + __expf(-u));
}

DEVINL void gl2lds16(const void* g, void* l) {
    __builtin_amdgcn_global_load_lds((__attribute__((address_space(1))) const unsigned int*)g,
                                     (__attribute__((address_space(3))) unsigned int*)l, 16, 0, 0);
}

// xor-swizzle position of element k within a row (groups of 64, chunks of 8)
DEVINL int swz(int k, int row) {
    return (k & ~63) | ((((k >> 3) ^ row) & 7) << 3) | (k & 7);
}

// ---------------- wfT builder: wfT[n=(k,e)][kk=(i,dd)] = s(i,k)*w_sed[j,dd,e]
__global__ __launch_bounds__(256) void build_wft(const float* __restrict__ w_sed,
                                                 unsigned short* __restrict__ wfT,
                                                 SedTab tab) {
    __shared__ float t[32][33];
    int n0 = blockIdx.y * 32, kk0 = blockIdx.x * 32;
    int k = n0 / 192, i = kk0 / 192;            // tiles never straddle (192 = 6*32)
    int j = tab.j[i * 16 + k];
    float s = (float)tab.s[i * 16 + k];
    int e0 = n0 - k * 192, dd0 = kk0 - i * 192;
    int tx = threadIdx.x & 31, ty = threadIdx.x >> 5;
    const float* base = w_sed + ((size_t)j * 192 + dd0) * 192 + e0;
    for (int it = 0; it < 4; ++it) {
        int row = ty + it * 8;                  // row = dd index, tx = e index
        t[row][tx] = base[(size_t)row * 192 + tx];
    }
    __syncthreads();
    unsigned short* ob = wfT + (size_t)n0 * 3072 + kk0;
    for (int it = 0; it < 4; ++it) {
        int row = ty + it * 8;                  // out row = e index, tx = dd index
        ob[(size_t)row * 3072 + tx] = f2bf(s * t[tx][row]);
    }
}

// ---------------- small weights → [N][K] bf16 (fc1/fc2 pre-swizzled) --------
__global__ __launch_bounds__(256) void prep_w(const float* __restrict__ proj,
                                              const float* __restrict__ fc1,
                                              const float* __restrict__ fc2,
                                              unsigned short* __restrict__ projT,
                                              unsigned short* __restrict__ fc1T,
                                              unsigned short* __restrict__ fc2T) {
    int t = blockIdx.x * 256 + threadIdx.x;     // grid covers 147456
    if (t < 192 * 192) projT[t] = f2bf(proj[(t % 192) * 192 + t / 192]);
    if (t < 768 * 192) {
        int n = t / 192, k = t % 192;
        fc1T[n * 192 + swz(k, n)] = f2bf(fc1[(size_t)k * 768 + n]);
    }
    if (t < 192 * 768) {
        int o = t / 768, k = t % 768;
        fc2T[o * 768 + swz(k, o)] = f2bf(fc2[(size_t)k * 192 + o]);
    }
}

// ---------------- LN1 over channels + windowize; also emit raw x (bf16) -----
__global__ __launch_bounds__(256) void ln1_win(const float* __restrict__ x,
                                               const float* __restrict__ g,
                                               const float* __restrict__ bta,
                                               unsigned short* __restrict__ xw,
                                               unsigned short* __restrict__ xwin) {
    __shared__ float vals[192 * 65];
    __shared__ float ps[8][64];
    __shared__ float mrs[2][64];
    int t = threadIdx.x;
    int bid = blockIdx.x;
    int x0 = (bid & 3) << 6;
    int y  = (bid >> 2) & 255;
    int b  = bid >> 10;
    int px = t & 63, cg = t >> 6;
    const float* xp = x + ((size_t)b * 192 * 65536) + (size_t)y * 256 + x0 + px;
    float s = 0.f, s2 = 0.f;
    for (int c = cg; c < 192; c += 4) {
        float v = xp[(size_t)c * 65536];
        vals[c * 65 + px] = v;
        s += v; s2 += v * v;
    }
    ps[cg][px] = s; ps[cg + 4][px] = s2;
    __syncthreads();
    if (t < 64) {
        float S  = ps[0][t] + ps[1][t] + ps[2][t] + ps[3][t];
        float S2 = ps[4][t] + ps[5][t] + ps[6][t] + ps[7][t];
        float mean = S * (1.0f / 192.0f);
        float var  = S2 * (1.0f / 192.0f) - mean * mean;
        mrs[0][t] = mean;
        mrs[1][t] = rsqrtf(var + 1e-5f);
    }
    __syncthreads();
    int wh = y >> 2, wr = y & 3;
    for (int i = t; i < 192 * 64; i += 256) {
        int p = i / 192;
        int c = i - p * 192;
        float v = vals[c * 65 + p];
        int xx = x0 + p;
        int ww = xx >> 2, wc = xx & 3;
        int gp = ((b * 64 + wh) * 64 + ww) * 16 + wr * 4 + wc;
        size_t o = (size_t)gp * 192 + c;
        xwin[o] = f2bf(v);
        xw[o] = f2bf((v - mrs[0][p]) * mrs[1][p] * g[c] + bta[c]);
    }
}

// ---------------- bf16 MFMA GEMM, TM x TN, BK=64, XOR-swizzled LDS ----------
// A:[M,K] row-major bf16, BT:[N,K] row-major bf16 (pre-transposed B).
// EPI 0: outB bf16 = gelu(acc [+bias])                        (gemm1 sedenion)
// EPI 3: xres(bf16) += acc+bias; outB = LN2(xres) bf16, col-swizzled (gemm2)
template<int TM, int TN, int EPI>
__global__ __launch_bounds__(256, 2) void gemm_bf16(
        const unsigned short* __restrict__ A, const unsigned short* __restrict__ BT,
        const float* __restrict__ bias, unsigned short* __restrict__ outB,
        unsigned short* __restrict__ xresb,
        const float* __restrict__ g2, const float* __restrict__ b2,
        int K, int N) {
    constexpr int WN = TN / 2;
    constexpr int NT = WN / 16;
    constexpr int MT = TM / 32;
    constexpr int HR = TM / 2;
    __shared__ __align__(16) char smem[(TM * 64 + TN * 64) * 2];
    short* lsA = (short*)smem;
    short* lsB = (short*)(smem + TM * 64 * 2);
    int tid = threadIdx.x, lane = tid & 63, wid = tid >> 6;
    int wrow = wid >> 1, wcol = wid & 1;
    int lm = lane & 15, lq = lane >> 4;
    int bm = blockIdx.x * TM, bn = blockIdx.y * TN;
    const unsigned short* Ag = A + (size_t)bm * K;
    const unsigned short* Bg = BT + (size_t)bn * K;
    f32x4 acc[MT][NT] = {};
    for (int k0 = 0; k0 < K; k0 += 64) {
        #pragma unroll
        for (int it = 0; it < TM / 32; ++it) {      // stage A tile
            int p = (it * 4 + wid) * 64 + lane;
            int r = p >> 3;
            int q = (p & 7) ^ (r & 7);
            gl2lds16(Ag + (size_t)r * K + k0 + q * 8, lsA + (it * 4 + wid) * 512);
        }
        #pragma unroll
        for (int it = 0; it < TN / 32; ++it) {      // stage BT tile
            int p = (it * 4 + wid) * 64 + lane;
            int r = p >> 3;
            int q = (p & 7) ^ (r & 7);
            gl2lds16(Bg + (size_t)r * K + k0 + q * 8, lsB + (it * 4 + wid) * 512);
        }
        __syncthreads();
        #pragma unroll
        for (int s = 0; s < 2; ++s) {
            short8 af[MT], bfr[NT];
            #pragma unroll
            for (int mt = 0; mt < MT; ++mt) {
                int r = wrow * HR + mt * 16 + lm;
                int q = s * 4 + lq;
                int pos = r * 8 + (q ^ (r & 7));
                af[mt] = *(const short8*)&lsA[pos * 8];
            }
            #pragma unroll
            for (int nt = 0; nt < NT; ++nt) {
                int r = wcol * WN + nt * 16 + lm;
                int q = s * 4 + lq;
                int pos = r * 8 + (q ^ (r & 7));
                bfr[nt] = *(const short8*)&lsB[pos * 8];
            }
            #pragma unroll
            for (int mt = 0; mt < MT; ++mt)
                #pragma unroll
                for (int nt = 0; nt < NT; ++nt)
                    acc[mt][nt] = __builtin_amdgcn_mfma_f32_16x16x32_bf16(af[mt], bfr[nt], acc[mt][nt], 0, 0, 0);
        }
        __syncthreads();
    }
    // epilogue: C/D layout col=lane&15, row=lq*4+reg
    int rowB = bm + wrow * HR + lq * 4;
    int colB = bn + wcol * WN + lm;

    if constexpr (EPI == 0) {
        #pragma unroll
        for (int mt = 0; mt < MT; ++mt)
            #pragma unroll
            for (int nt = 0; nt < NT; ++nt)
                #pragma unroll
                for (int r = 0; r < 4; ++r) {
                    int gr = rowB + mt * 16 + r;
                    int gc = colB + nt * 16;
                    float v = acc[mt][nt][r];
                    if (bias) v += bias[gc];
                    outB[(size_t)gr * N + gc] = f2bf(gelu_f(v));
                }
    } else {
        // proj + residual into xres (bf16, in-place over xwin), fused LN2 →
        // outB (A3, col-swizzled for ffn_fused). TM=128, TN=192, bn=0.
        float sA[MT][4], s2A[MT][4];
        #pragma unroll
        for (int mt = 0; mt < MT; ++mt)
            #pragma unroll
            for (int r = 0; r < 4; ++r) { sA[mt][r] = 0.f; s2A[mt][r] = 0.f; }
        #pragma unroll
        for (int mt = 0; mt < MT; ++mt)
            #pragma unroll
            for (int nt = 0; nt < NT; ++nt)
                #pragma unroll
                for (int r = 0; r < 4; ++r) {
                    int gr = rowB + mt * 16 + r;
                    int gc = colB + nt * 16;
                    size_t o = (size_t)gr * 192 + gc;
                    float v = bf2f(xresb[o]) + acc[mt][nt][r] + bias[gc];
                    xresb[o] = f2bf(v);
                    acc[mt][nt][r] = v;
                    sA[mt][r] += v; s2A[mt][r] += v * v;
                }
        #pragma unroll
        for (int mt = 0; mt < MT; ++mt)
            #pragma unroll
            for (int r = 0; r < 4; ++r)
                #pragma unroll
                for (int msk = 1; msk < 16; msk <<= 1) {
                    sA[mt][r]  += __shfl_xor(sA[mt][r],  msk, 64);
                    s2A[mt][r] += __shfl_xor(s2A[mt][r], msk, 64);
                }
        float* psS   = (float*)smem;             // [128][2]
        float* psS2  = psS + 256;                // [128][2]
        float* pmean = psS2 + 256;               // [128]
        float* prsig = pmean + 128;              // [128]
        if (lm == 0) {
            #pragma unroll
            for (int mt = 0; mt < MT; ++mt)
                #pragma unroll
                for (int r = 0; r < 4; ++r) {
                    int rl = wrow * HR + mt * 16 + lq * 4 + r;
                    psS [rl * 2 + wcol] = sA[mt][r];
                    psS2[rl * 2 + wcol] = s2A[mt][r];
                }
        }
        __syncthreads();
        if (tid < TM) {
            float S  = psS[tid * 2]  + psS[tid * 2 + 1];
            float S2 = psS2[tid * 2] + psS2[tid * 2 + 1];
            float mean = S * (1.0f / 192.0f);
            float var  = S2 * (1.0f / 192.0f) - mean * mean;
            pmean[tid] = mean;
            prsig[tid] = rsqrtf(var + 1e-5f);
        }
        __syncthreads();
        float gw[NT], bw[NT];
        #pragma unroll
        for (int nt = 0; nt < NT; ++nt) {
            int gc = colB + nt * 16;
            gw[nt] = g2[gc]; bw[nt] = b2[gc];
        }
        #pragma unroll
        for (int mt = 0; mt < MT; ++mt)
            #pragma unroll
            for (int nt = 0; nt < NT; ++nt)
                #pragma unroll
                for (int r = 0; r < 4; ++r) {
                    int gr = rowB + mt * 16 + r;
                    int rl = wrow * HR + mt * 16 + lq * 4 + r;
                    int gc = colB + nt * 16;
                    float v = (acc[mt][nt][r] - pmean[rl]) * prsig[rl] * gw[nt] + bw[nt];
                    outB[(size_t)gr * 192 + swz(gc, gr)] = f2bf(v);
                }
    }
}

// ---------------- fused FFN: out = scatter(xres + gelu(A3@fc1+b1)@fc2 + b2) -
// A3: [131072][192] bf16 col-swizzled; fc1T [768][192], fc2T [192][768]
// pre-swizzled; xres bf16 plain. One block = 64 windowed-pixel rows.
__global__ __launch_bounds__(256, 2) void ffn_fused(
        const unsigned short* __restrict__ A3, const unsigned short* __restrict__ fc1T,
        const unsigned short* __restrict__ fc2T, const float* __restrict__ b1,
        const float* __restrict__ b2, const unsigned short* __restrict__ xresb,
        float* __restrict__ outF) {
    __shared__ __align__(16) char smem[81920];
    short* A3s = (short*)smem;                    // [64][192]
    short* wA  = (short*)(smem + 24576);          // [64][192]  fc1 slice
    short* wB  = (short*)(smem + 49152);          // [192][64]  fc2 slice
    short* Sb  = (short*)(smem + 73728);          // [64][64]   gelu tile
    int tid = threadIdx.x, lane = tid & 63, wid = tid >> 6;
    int wrow = wid >> 1, wcol = wid & 1;
    int lm = lane & 15, lq = lane >> 4;
    int bm = blockIdx.x * 64;

    const unsigned short* A3g = A3 + (size_t)bm * 192;     // tile contiguous
    #pragma unroll
    for (int it = 0; it < 6; ++it) {
        int ch = (it * 4 + wid) * 64 + lane;
        gl2lds16(A3g + ch * 8, A3s + (it * 4 + wid) * 512);
    }

    f32x4 acc2[2][6] = {};
    for (int nb = 0; nb < 12; ++nb) {
        const unsigned short* f1g = fc1T + (size_t)nb * 64 * 192;  // contiguous
        #pragma unroll
        for (int it = 0; it < 6; ++it) {
            int ch = (it * 4 + wid) * 64 + lane;
            gl2lds16(f1g + ch * 8, wA + (it * 4 + wid) * 512);
        }
        int kb = nb * 64;
        #pragma unroll
        for (int it = 0; it < 6; ++it) {
            int ch = (it * 4 + wid) * 64 + lane;               // 8 chunks/row
            gl2lds16(fc2T + (size_t)(ch >> 3) * 768 + kb + (ch & 7) * 8,
                     wB + (it * 4 + wid) * 512);
        }
        __syncthreads();
        // phase A: S = gelu(A3 @ fc1slice + b1)
        f32x4 acc1[2][2] = {};
        #pragma unroll
        for (int ks = 0; ks < 6; ++ks) {
            int c = ks * 4 + lq;
            short8 af[2], bfr[2];
            #pragma unroll
            for (int mt = 0; mt < 2; ++mt) {
                int r = wrow * 32 + mt * 16 + lm;
                int slot = (c & ~7) | ((c ^ r) & 7);
                af[mt] = *(const short8*)&A3s[r * 192 + slot * 8];
            }
            #pragma unroll
            for (int nt = 0; nt < 2; ++nt) {
                int n = wcol * 32 + nt * 16 + lm;
                int slot = (c & ~7) | ((c ^ n) & 7);
                bfr[nt] = *(const short8*)&wA[n * 192 + slot * 8];
            }
            #pragma unroll
            for (int mt = 0; mt < 2; ++mt)
                #pragma unroll
                for (int nt = 0; nt < 2; ++nt)
                    acc1[mt][nt] = __builtin_amdgcn_mfma_f32_16x16x32_bf16(af[mt], bfr[nt], acc1[mt][nt], 0, 0, 0);
        }
        #pragma unroll
        for (int nt = 0; nt < 2; ++nt) {
            int cl = wcol * 32 + nt * 16 + lm;
            float bv = b1[nb * 64 + cl];
            #pragma unroll
            for (int mt = 0; mt < 2; ++mt)
                #pragma unroll
                for (int r = 0; r < 4; ++r) {
                    int row = wrow * 32 + mt * 16 + lq * 4 + r;
                    float v = gelu_f(acc1[mt][nt][r] + bv);
                    int slot = ((cl >> 3) ^ row) & 7;
                    Sb[row * 64 + slot * 8 + (cl & 7)] = f2bf(v);
                }
        }
        __syncthreads();
        // phase B: acc2 += S @ fc2slice
        #pragma unroll
        for (int ks = 0; ks < 2; ++ks) {
            int c = ks * 4 + lq;                 // chunk 0..7
            short8 sf[2], wf[6];
            #pragma unroll
            for (int mt = 0; mt < 2; ++mt) {
                int r = wrow * 32 + mt * 16 + lm;
                int slot = (c ^ r) & 7;
                sf[mt] = *(const short8*)&Sb[r * 64 + slot * 8];
            }
            #pragma unroll
            for (int nt = 0; nt < 6; ++nt) {
                int o = wcol * 96 + nt * 16 + lm;
                int slot = (c ^ o) & 7;
                wf[nt] = *(const short8*)&wB[o * 64 + slot * 8];
            }
            #pragma unroll
            for (int mt = 0; mt < 2; ++mt)
                #pragma unroll
                for (int nt = 0; nt < 6; ++nt)
                    acc2[mt][nt] = __builtin_amdgcn_mfma_f32_16x16x32_bf16(sf[mt], wf[nt], acc2[mt][nt], 0, 0, 0);
        }
        __syncthreads();
    }
    // epilogue: + b2 + xres, transpose in LDS, coalesced BCHW scatter
    float* T = (float*)smem;                     // [64][201]
    #pragma unroll
    for (int nt = 0; nt < 6; ++nt) {
        int col = wcol * 96 + nt * 16 + lm;
        float bv = b2[col];
        #pragma unroll
        for (int mt = 0; mt < 2; ++mt)
            #pragma unroll
            for (int r = 0; r < 4; ++r) {
                int row = wrow * 32 + mt * 16 + lq * 4 + r;
                float xr = bf2f(xresb[(size_t)(bm + row) * 192 + col]);
                T[row * 201 + col] = acc2[mt][nt][r] + bv + xr;
            }
    }
    __syncthreads();
    int b  = bm >> 16;
    int wh = (bm >> 10) & 63;
    int ww0 = (bm >> 4) & 63;
    int ybase = wh * 4, xbase = ww0 * 4;
    for (int idx = tid; idx < 3072; idx += 256) {
        int xq = idx & 3, run = idx >> 2;
        int c = run >> 2, wr = run & 3;
        int p = xq * 16 + wr * 4;
        f32x4 val;
        val[0] = T[(p + 0) * 201 + c];
        val[1] = T[(p + 1) * 201 + c];
        val[2] = T[(p + 2) * 201 + c];
        val[3] = T[(p + 3) * 201 + c];
        size_t o = (((size_t)b * 192 + c) * 256 + (ybase + wr)) * 256 + xbase + xq * 4;
        *(f32x4*)&outF[o] = val;
    }
}

// ---------------- launch ----------------------------------------------------
extern "C" void kernel_launch(void* const* d_in, const int* in_sizes, int n_in,
                              void* d_out, int out_size, void* d_ws, size_t ws_size,
                              hipStream_t stream) {
    const float* x      = (const float*)d_in[0];
    const float* n1g    = (const float*)d_in[1];
    const float* n1b    = (const float*)d_in[2];
    const float* w_sed  = (const float*)d_in[3];
    const float* proj_w = (const float*)d_in[4];
    const float* proj_b = (const float*)d_in[5];
    const float* n2g    = (const float*)d_in[6];
    const float* n2b    = (const float*)d_in[7];
    const float* fc1_w  = (const float*)d_in[8];
    const float* fc1_b  = (const float*)d_in[9];
    const float* fc2_w  = (const float*)d_in[10];
    const float* fc2_b  = (const float*)d_in[11];
    float* out = (float*)d_out;

    char* ws = (char*)d_ws;
    unsigned short* wfT   = (unsigned short*)(ws);                 // 18,874,368 B
    unsigned short* xw    = (unsigned short*)(ws + 18874368);      // 50,331,648 B
    unsigned short* A2    = (unsigned short*)(ws + 69206016);      // 50,331,648 B (later A3, aliased safely)
    unsigned short* xresb = (unsigned short*)(ws + 119537664);     // 50,331,648 B (xwin, then xres in-place)
    unsigned short* projT = (unsigned short*)(ws + 169869312);     // 73,728 B
    unsigned short* fc1T  = (unsigned short*)(ws + 169943040);     // 294,912 B
    unsigned short* fc2T  = (unsigned short*)(ws + 170237952);     // 294,912 B (end 170,532,864)
    unsigned short* A3    = A2;   // EPI3 writes A3 rows only after reading same A2 rows — safe

    build_wft<<<dim3(96, 96), 256, 0, stream>>>(w_sed, wfT, g_sed);
    prep_w<<<576, 256, 0, stream>>>(proj_w, fc1_w, fc2_w, projT, fc1T, fc2T);
    ln1_win<<<2048, 256, 0, stream>>>(x, n1g, n1b, xw, xresb);

    // sedenion GEMM: [8192,3072]@[3072,3072] → gelu → A2 (≡ [131072,192])
    gemm_bf16<128, 128, 0><<<dim3(64, 24), 256, 0, stream>>>(
        xw, wfT, nullptr, A2, nullptr, nullptr, nullptr, 3072, 3072);
    // proj GEMM + residual(bf16, in-place) + fused LN2 → A3 (swizzled)
    gemm_bf16<128, 192, 3><<<dim3(1024, 1), 256, 0, stream>>>(
        A2, projT, proj_b, A3, xresb, n2g, n2b, 192, 192);
    // fused FFN: fc1+gelu+fc2+residual+BCHW scatter, H1 never hits HBM
    ffn_fused<<<2048, 256, 0, stream>>>(A3, fc1T, fc2T, fc1_b, fc2_b, xresb, out);
}